// Round 6
// baseline (699.028 us; speedup 1.0000x reference)
//
#include <hip/hip_runtime.h>

#define N_NODES 10000
#define N_EDGES 640000
#define CH 128
#define NHB 128              // hist/scatter edge partitions
#define EPB (N_EDGES / NHB)  // 5000 edges per partition
#define NCHUNK 40            // ceil(N_NODES/256)
#define GT 157               // ceil(N_NODES/64) gemm tiles
#define NBLK_A 256
#define NBLK_B 512
#define NTHR 256

// ---------------------------------------------------------------------------
// Grid-wide soft barrier (all blocks co-resident by construction).
__device__ __forceinline__ void gridbar(int* ctr, int target) {
    __threadfence();
    __syncthreads();
    if (threadIdx.x == 0) {
        atomicAdd(ctr, 1);
        while (__hip_atomic_load(ctr, __ATOMIC_RELAXED, __HIP_MEMORY_SCOPE_AGENT) < target)
            __builtin_amdgcn_s_sleep(2);
    }
    __syncthreads();
    __threadfence();
}

// ---------------------------------------------------------------------------
// One 64-row x 128-col tile of out[m][o] = sum_k A[m][k]*W[o][k].
// float4 LDS reads: 3x ds_read_b128 per k-step instead of 12x b32.
__device__ __forceinline__ void gemm_tile(const float* __restrict__ A,
        const float* __restrict__ W, float* __restrict__ out, int tile,
        float (*As)[68], float (*Ws)[132]) {
    int tid = threadIdx.x;
    int tx = tid & 31;
    int ty = tid >> 5;
    int row0 = tile * 64;
    float4 acc[8];
    #pragma unroll
    for (int j = 0; j < 8; ++j) acc[j] = make_float4(0.f, 0.f, 0.f, 0.f);
    for (int k0 = 0; k0 < 128; k0 += 32) {
        #pragma unroll
        for (int i = 0; i < 8; ++i) {
            int idx = tid + i * 256;
            int r = idx >> 5, k = idx & 31;
            int gr = row0 + r;
            As[k][r] = (gr < N_NODES) ? A[gr * CH + k0 + k] : 0.0f;
        }
        #pragma unroll
        for (int i = 0; i < 16; ++i) {
            int idx = tid + i * 256;
            int o = idx >> 5, k = idx & 31;
            Ws[k][o] = W[o * CH + k0 + k];
        }
        __syncthreads();
        #pragma unroll
        for (int kk = 0; kk < 32; ++kk) {
            float4 a03 = *reinterpret_cast<const float4*>(&As[kk][ty * 8]);
            float4 a47 = *reinterpret_cast<const float4*>(&As[kk][ty * 8 + 4]);
            float4 w   = *reinterpret_cast<const float4*>(&Ws[kk][tx * 4]);
            acc[0].x += a03.x * w.x; acc[0].y += a03.x * w.y; acc[0].z += a03.x * w.z; acc[0].w += a03.x * w.w;
            acc[1].x += a03.y * w.x; acc[1].y += a03.y * w.y; acc[1].z += a03.y * w.z; acc[1].w += a03.y * w.w;
            acc[2].x += a03.z * w.x; acc[2].y += a03.z * w.y; acc[2].z += a03.z * w.z; acc[2].w += a03.z * w.w;
            acc[3].x += a03.w * w.x; acc[3].y += a03.w * w.y; acc[3].z += a03.w * w.z; acc[3].w += a03.w * w.w;
            acc[4].x += a47.x * w.x; acc[4].y += a47.x * w.y; acc[4].z += a47.x * w.z; acc[4].w += a47.x * w.w;
            acc[5].x += a47.y * w.x; acc[5].y += a47.y * w.y; acc[5].z += a47.y * w.z; acc[5].w += a47.y * w.w;
            acc[6].x += a47.z * w.x; acc[6].y += a47.z * w.y; acc[6].z += a47.z * w.z; acc[6].w += a47.z * w.w;
            acc[7].x += a47.w * w.x; acc[7].y += a47.w * w.y; acc[7].z += a47.w * w.z; acc[7].w += a47.w * w.w;
        }
        __syncthreads();
    }
    #pragma unroll
    for (int j = 0; j < 8; ++j) {
        int gr = row0 + ty * 8 + j;
        if (gr < N_NODES)
            *reinterpret_cast<float4*>(&out[gr * CH + tx * 4]) = acc[j];
    }
}

// ---------------------------------------------------------------------------
union SMemA {
    struct { int h[N_NODES]; float hf[N_NODES]; } hist;    // 80 KB
    struct { int cur[N_NODES]; float di[N_NODES]; } scat;  // 80 KB
    struct { float As[32][68]; float Ws[32][132]; } gemm;  // ~26 KB
    struct { int csum[NCHUNK]; int wsum[4]; } scan;
    int red[4];
};

// Kernel A: CSR build, with GEMM1 + conv-fold overlapped on blocks 128..255.
__global__ __launch_bounds__(NTHR) void build_kernel(
        const float* __restrict__ x, const int* __restrict__ ei,
        const float* __restrict__ ew, const float* __restrict__ W1,
        const float* __restrict__ conv_w, const float* __restrict__ conv_b,
        const float* __restrict__ fc_w, const float* __restrict__ fc_b,
        float* __restrict__ xw1, int2* __restrict__ erec,
        int* __restrict__ hist, float* __restrict__ dhist,
        int* __restrict__ tot, int* __restrict__ offs, float* __restrict__ dinv,
        int* __restrict__ csum, float* __restrict__ vbuf, float* __restrict__ c0,
        int* __restrict__ ctr) {
    __shared__ SMemA sm;
    const int b = blockIdx.x, t = threadIdx.x;

    // ---- Phase 1: hist (0..127)  ||  gemm1 + conv-fold (128..255) ----
    if (b < NHB) {
        for (int i = t; i < N_NODES; i += NTHR) { sm.hist.h[i] = 0; sm.hist.hf[i] = 0.0f; }
        __syncthreads();
        int e0 = b * EPB;
        for (int i = t; i < EPB; i += NTHR) {
            int c = ei[N_EDGES + e0 + i];
            float w = ew[e0 + i];
            atomicAdd(&sm.hist.h[c], 1);       // LDS atomics
            atomicAdd(&sm.hist.hf[c], w);
        }
        __syncthreads();
        for (int i = t; i < N_NODES; i += NTHR) {
            hist[b * N_NODES + i] = sm.hist.h[i];
            dhist[b * N_NODES + i] = sm.hist.hf[i];
        }
    } else {
        int t1 = b - NHB;
        gemm_tile(x, W1, xw1, t1, sm.gemm.As, sm.gemm.Ws);
        if (t1 + 128 < GT) gemm_tile(x, W1, xw1, t1 + 128, sm.gemm.As, sm.gemm.Ws);
        if (b == NBLK_A - 1) {                 // conv1d+fc weight folding
            for (int i = t; i <= 384; i += NTHR) {
                if (i < 384) {
                    float s = 0.0f;
                    for (int o = 0; o < CH; ++o) s += fc_w[o] * conv_w[o * 384 + i];
                    vbuf[i] = s;
                } else {
                    float s = fc_b[0];
                    for (int o = 0; o < CH; ++o) s += fc_w[o] * conv_b[o];
                    *c0 = s;
                }
            }
        }
    }
    gridbar(ctr, NBLK_A * 1);

    // ---- Phase 2: reduce hist -> tot, dinv, per-chunk sums ----
    if (b < NCHUNK) {
        int n = b * NTHR + t;
        int c = 0;
        if (n < N_NODES) {
            float d = 0.0f;
            #pragma unroll 4
            for (int bb = 0; bb < NHB; ++bb) {
                c += hist[bb * N_NODES + n];
                d += dhist[bb * N_NODES + n];
            }
            tot[n] = c;
            dinv[n] = rsqrtf(d + 1.0f);        // +1 = self-loop weight
        }
        int lane = t & 63, wave = t >> 6;
        int s = c;
        #pragma unroll
        for (int off = 32; off > 0; off >>= 1) s += __shfl_down(s, off, 64);
        if (lane == 0) sm.red[wave] = s;
        __syncthreads();
        if (t == 0) csum[b] = sm.red[0] + sm.red[1] + sm.red[2] + sm.red[3];
    }
    gridbar(ctr, NBLK_A * 2);

    // ---- Phase 3: offs = exclusive prefix; hist columns -> start cursors ----
    if (b < NCHUNK) {
        if (t < NCHUNK) sm.scan.csum[t] = csum[t];
        __syncthreads();
        int base = 0;
        for (int i = 0; i < b; ++i) base += sm.scan.csum[i];
        int n = b * NTHR + t;
        int v = (n < N_NODES) ? tot[n] : 0;
        int lane = t & 63, wave = t >> 6;
        int s = v;
        #pragma unroll
        for (int off = 1; off < 64; off <<= 1) {
            int u = __shfl_up(s, off, 64);
            if (lane >= off) s += u;
        }
        if (lane == 63) sm.scan.wsum[wave] = s;
        __syncthreads();
        int wbase = 0;
        for (int i = 0; i < wave; ++i) wbase += sm.scan.wsum[i];
        if (n < N_NODES) {
            int run = base + wbase + s - v;
            offs[n] = run;
            for (int bb = 0; bb < NHB; ++bb) {
                int hh = hist[bb * N_NODES + n];
                hist[bb * N_NODES + n] = run;
                run += hh;
            }
        }
    }
    gridbar(ctr, NBLK_A * 3);

    // ---- Phase 4: scatter edges into CSR {src,val} records ----
    if (b < NHB) {
        for (int i = t; i < N_NODES; i += NTHR) {
            sm.scat.cur[i] = hist[b * N_NODES + i];
            sm.scat.di[i] = dinv[i];
        }
        __syncthreads();
        int e0 = b * EPB;
        for (int i = t; i < EPB; i += NTHR) {
            int e = e0 + i;
            int r = ei[e];
            int c = ei[N_EDGES + e];
            int p = atomicAdd(&sm.scat.cur[c], 1);   // LDS atomic
            float v = sm.scat.di[r] * ew[e] * sm.scat.di[c];
            erec[p] = make_int2(r, __float_as_int(v));
        }
    }
}

// ---------------------------------------------------------------------------
// Aggregation phase for kernel B: 32 lanes/node, 8 nodes/block-iter,
// grid-stride, edge loop unrolled x16 (MLP at 2 blocks/CU occupancy).
__device__ __forceinline__ void agg_phase(const float4* __restrict__ xw4,
        const int2* __restrict__ erec, const int* __restrict__ offs,
        const int* __restrict__ cnt, const float* __restrict__ dinv,
        const float4* __restrict__ bias4, float4* __restrict__ out4) {
    int l = threadIdx.x & 31;
    int g = threadIdx.x >> 5;
    for (int n = blockIdx.x * 8 + g; n < N_NODES; n += NBLK_B * 8) {
        float d = dinv[n];
        float dd = d * d;
        float4 self = xw4[n * 32 + l];
        float4 acc = make_float4(dd * self.x, dd * self.y, dd * self.z, dd * self.w);
        int start = offs[n];
        int num = cnt[n];
        int i = 0;
        for (; i + 16 <= num; i += 16) {
            int2 r[16];
            #pragma unroll
            for (int j = 0; j < 16; ++j) r[j] = erec[start + i + j];
            float4 f[16];
            #pragma unroll
            for (int j = 0; j < 16; ++j) f[j] = xw4[r[j].x * 32 + l];
            #pragma unroll
            for (int j = 0; j < 16; ++j) {
                float v = __int_as_float(r[j].y);
                acc.x += v * f[j].x; acc.y += v * f[j].y;
                acc.z += v * f[j].z; acc.w += v * f[j].w;
            }
        }
        for (; i + 4 <= num; i += 4) {
            int2 r[4];
            #pragma unroll
            for (int j = 0; j < 4; ++j) r[j] = erec[start + i + j];
            #pragma unroll
            for (int j = 0; j < 4; ++j) {
                float4 f = xw4[r[j].x * 32 + l];
                float v = __int_as_float(r[j].y);
                acc.x += v * f.x; acc.y += v * f.y; acc.z += v * f.z; acc.w += v * f.w;
            }
        }
        for (; i < num; ++i) {
            int2 r = erec[start + i];
            float4 f = xw4[r.x * 32 + l];
            float v = __int_as_float(r.y);
            acc.x += v * f.x; acc.y += v * f.y; acc.z += v * f.z; acc.w += v * f.w;
        }
        float4 bb = bias4[l];
        acc.x = fmaxf(acc.x + bb.x, 0.0f);
        acc.y = fmaxf(acc.y + bb.y, 0.0f);
        acc.z = fmaxf(acc.z + bb.z, 0.0f);
        acc.w = fmaxf(acc.w + bb.w, 0.0f);
        out4[n * 32 + l] = acc;
    }
}

// Kernel B: agg1 -> gemm2 -> agg2 -> convfc.  Small LDS, 2 blocks/CU guaranteed.
__global__ __launch_bounds__(NTHR, 2) void compute_kernel(
        const float* __restrict__ b1, const float* __restrict__ W2,
        const float* __restrict__ b2,
        const float* __restrict__ xw1, float* __restrict__ h1,
        float* __restrict__ xw2, float* __restrict__ h2,
        const int2* __restrict__ erec, const int* __restrict__ offs,
        const int* __restrict__ tot, const float* __restrict__ dinv,
        const float* __restrict__ vbuf, const float* __restrict__ c0,
        float* __restrict__ out, int* __restrict__ ctr) {
    __shared__ struct { float As[32][68]; float Ws[32][132]; } sm;
    const int b = blockIdx.x, t = threadIdx.x;

    // ---- layer-1 aggregation ----
    agg_phase((const float4*)xw1, erec, offs, tot, dinv, (const float4*)b1, (float4*)h1);
    gridbar(ctr, NBLK_B * 1);

    // ---- gemm2 ----
    if (b < GT) gemm_tile(h1, W2, xw2, b, sm.As, sm.Ws);
    gridbar(ctr, NBLK_B * 2);

    // ---- layer-2 aggregation ----
    agg_phase((const float4*)xw2, erec, offs, tot, dinv, (const float4*)b2, (float4*)h2);
    gridbar(ctr, NBLK_B * 3);

    // ---- fused temporal conv + fc ----
    {
        int l = t & 31;
        int g = t >> 5;
        const float4* h4 = (const float4*)h2;
        float v00 = vbuf[(4 * l + 0) * 3 + 0], v01 = vbuf[(4 * l + 0) * 3 + 1], v02 = vbuf[(4 * l + 0) * 3 + 2];
        float v10 = vbuf[(4 * l + 1) * 3 + 0], v11 = vbuf[(4 * l + 1) * 3 + 1], v12 = vbuf[(4 * l + 1) * 3 + 2];
        float v20 = vbuf[(4 * l + 2) * 3 + 0], v21 = vbuf[(4 * l + 2) * 3 + 1], v22 = vbuf[(4 * l + 2) * 3 + 2];
        float v30 = vbuf[(4 * l + 3) * 3 + 0], v31 = vbuf[(4 * l + 3) * 3 + 1], v32 = vbuf[(4 * l + 3) * 3 + 2];
        float cc = *c0;
        for (int n = b * 8 + g; n < N_NODES; n += NBLK_B * 8) {
            float4 hm = h4[n * 32 + l];
            float p = hm.x * v01 + hm.y * v11 + hm.z * v21 + hm.w * v31;
            if (n > 0) {
                float4 ha = h4[(n - 1) * 32 + l];
                p += ha.x * v00 + ha.y * v10 + ha.z * v20 + ha.w * v30;
            }
            if (n < N_NODES - 1) {
                float4 hb = h4[(n + 1) * 32 + l];
                p += hb.x * v02 + hb.y * v12 + hb.z * v22 + hb.w * v32;
            }
            #pragma unroll
            for (int off = 16; off > 0; off >>= 1) p += __shfl_down(p, off, 32);
            if (l == 0) out[n] = p + cc;
        }
    }
}

// ---------------------------------------------------------------------------
extern "C" void kernel_launch(void* const* d_in, const int* in_sizes, int n_in,
                              void* d_out, int out_size, void* d_ws, size_t ws_size,
                              hipStream_t stream) {
    const float* x       = (const float*)d_in[0];
    const int*   ei      = (const int*)d_in[1];
    const float* ew      = (const float*)d_in[2];
    const float* W1      = (const float*)d_in[3];
    const float* b1      = (const float*)d_in[4];
    const float* W2      = (const float*)d_in[5];
    const float* b2      = (const float*)d_in[6];
    const float* conv_w  = (const float*)d_in[7];
    const float* conv_b  = (const float*)d_in[8];
    const float* fc_w    = (const float*)d_in[9];
    const float* fc_b    = (const float*)d_in[10];
    float* out = (float*)d_out;

    // Workspace (~36 MB, no aliasing — gemm1 overlaps the CSR build).
    float* xw1   = (float*)d_ws;                    // 1,280,000 f
    float* h1    = xw1 + N_NODES * CH;              // 1,280,000 f
    float* xw2   = h1 + N_NODES * CH;               // 1,280,000 f
    float* h2    = xw2 + N_NODES * CH;              // 1,280,000 f
    int2*  erec  = (int2*)(h2 + N_NODES * CH);      // 640,000 x 8B
    int*   hist  = (int*)(erec + N_EDGES);          // NHB*10,000 i
    float* dhist = (float*)(hist + NHB * N_NODES);  // NHB*10,000 f
    int*   tot   = (int*)(dhist + NHB * N_NODES);   // 10,000 i
    int*   offs  = tot + N_NODES;                   // 10,000 i
    float* dinv  = (float*)(offs + N_NODES);        // 10,000 f
    int*   csum  = (int*)(dinv + N_NODES);          // NCHUNK i
    float* vbuf  = (float*)(csum + NCHUNK);         // 384 f
    float* c0    = vbuf + 384;                      // 1 f
    int*   ctrA  = (int*)(c0 + 1);                  // 1 i
    int*   ctrB  = ctrA + 1;                        // 1 i

    hipMemsetAsync(ctrA, 0, 2 * sizeof(int), stream);

    build_kernel<<<NBLK_A, NTHR, 0, stream>>>(x, ei, ew, W1, conv_w, conv_b,
                                              fc_w, fc_b, xw1, erec, hist, dhist,
                                              tot, offs, dinv, csum, vbuf, c0, ctrA);

    compute_kernel<<<NBLK_B, NTHR, 0, stream>>>(b1, W2, b2, xw1, h1, xw2, h2,
                                                erec, offs, tot, dinv, vbuf, c0,
                                                out, ctrB);
}

// Round 7
// 236.363 us; speedup vs baseline: 2.9574x; 2.9574x over previous
//
#include <hip/hip_runtime.h>

#define N_NODES 10000
#define N_EDGES 640000
#define CH 128
#define NHB 128              // hist/scatter edge partitions
#define EPB (N_EDGES / NHB)  // 5000 edges per partition
#define NCHUNK 40            // ceil(N_NODES/256)

// ---------------------------------------------------------------------------
// Phase A: per-block LDS histograms — single pass, count + weighted degree
// in 80 KB LDS. No global atomics.
__global__ __launch_bounds__(256) void hist_kernel(const int* __restrict__ ei,
                                                   const float* __restrict__ ew,
                                                   int* __restrict__ hist,
                                                   float* __restrict__ dhist) {
    __shared__ int h[N_NODES];                 // 40 KB
    __shared__ float hf[N_NODES];              // 40 KB
    int b = blockIdx.x, t = threadIdx.x;
    for (int i = t; i < N_NODES; i += 256) { h[i] = 0; hf[i] = 0.0f; }
    __syncthreads();
    int e0 = b * EPB;
    for (int i = t; i < EPB; i += 256) {
        int c = ei[N_EDGES + e0 + i];
        float w = ew[e0 + i];
        atomicAdd(&h[c], 1);                   // LDS atomics
        atomicAdd(&hf[c], w);
    }
    __syncthreads();
    for (int i = t; i < N_NODES; i += 256) {
        hist[b * N_NODES + i] = h[i];
        dhist[b * N_NODES + i] = hf[i];
    }
}

// ---------------------------------------------------------------------------
// Phase B: reduce histograms -> tot, dinv. Extra block folds conv+fc weights.
__global__ __launch_bounds__(256) void reduce_kernel(const int* __restrict__ hist,
        const float* __restrict__ dhist, int* __restrict__ tot,
        float* __restrict__ dinv,
        const float* __restrict__ conv_w, const float* __restrict__ conv_b,
        const float* __restrict__ fc_w, const float* __restrict__ fc_b,
        float* __restrict__ vbuf, float* __restrict__ c0) {
    int blk = blockIdx.x, t = threadIdx.x;
    if (blk == NCHUNK) {                       // conv1d+fc weight folding
        for (int i = t; i <= 384; i += 256) {
            if (i < 384) {
                float s = 0.0f;
                for (int o = 0; o < CH; ++o) s += fc_w[o] * conv_w[o * 384 + i];
                vbuf[i] = s;
            } else {
                float s = fc_b[0];
                for (int o = 0; o < CH; ++o) s += fc_w[o] * conv_b[o];
                *c0 = s;
            }
        }
        return;
    }
    int n = blk * 256 + t;
    if (n >= N_NODES) return;
    int c = 0; float d = 0.0f;
    #pragma unroll 4
    for (int b = 0; b < NHB; ++b) {
        c += hist[b * N_NODES + n];
        d += dhist[b * N_NODES + n];
    }
    tot[n] = c;
    dinv[n] = rsqrtf(d + 1.0f);                // +1 = self-loop weight
}

// ---------------------------------------------------------------------------
// Phase C: offs[n] = exclusive prefix of tot; hist columns -> start cursors.
// Chunk base computed by block-summing tot[0 .. blk*256) directly (no csum).
__global__ __launch_bounds__(256) void bofs_kernel(int* __restrict__ hist,
        const int* __restrict__ tot, int* __restrict__ offs) {
    __shared__ int wred[4];
    __shared__ int wsum[4];
    __shared__ int base_s;
    int blk = blockIdx.x, t = threadIdx.x;
    int lane = t & 63, wave = t >> 6;
    // (a) base = sum of tot[0 .. blk*256)
    int partial = 0;
    int lim = blk * 256;
    for (int i = t; i < lim; i += 256) partial += tot[i];
    int s = partial;
    #pragma unroll
    for (int off = 32; off > 0; off >>= 1) s += __shfl_down(s, off, 64);
    if (lane == 0) wred[wave] = s;
    __syncthreads();
    if (t == 0) base_s = wred[0] + wred[1] + wred[2] + wred[3];
    __syncthreads();
    int base = base_s;
    // (b) local inclusive scan of this chunk's 256 tot values
    int n = blk * 256 + t;
    int v = (n < N_NODES) ? tot[n] : 0;
    s = v;
    #pragma unroll
    for (int off = 1; off < 64; off <<= 1) {
        int u = __shfl_up(s, off, 64);
        if (lane >= off) s += u;
    }
    if (lane == 63) wsum[wave] = s;
    __syncthreads();
    int wbase = 0;
    for (int i = 0; i < wave; ++i) wbase += wsum[i];
    // (c) write offs; convert hist column to per-block start cursors
    if (n < N_NODES) {
        int run = base + wbase + s - v;        // global exclusive prefix
        offs[n] = run;
        for (int b = 0; b < NHB; ++b) {
            int hh = hist[b * N_NODES + n];
            hist[b * N_NODES + n] = run;
            run += hh;
        }
    }
}

// ---------------------------------------------------------------------------
// Phase D: scatter edges into CSR order; packed {src, val} 8B records.
__global__ __launch_bounds__(256) void scatter_kernel(const int* __restrict__ ei,
        const float* __restrict__ ew, const float* __restrict__ dinv,
        const int* __restrict__ bofs, int2* __restrict__ erec) {
    __shared__ int cur[N_NODES];               // 40 KB
    __shared__ float di[N_NODES];              // 40 KB
    int b = blockIdx.x, t = threadIdx.x;
    for (int i = t; i < N_NODES; i += 256) {
        cur[i] = bofs[b * N_NODES + i];
        di[i] = dinv[i];
    }
    __syncthreads();
    int e0 = b * EPB;
    for (int i = t; i < EPB; i += 256) {
        int e = e0 + i;
        int r = ei[e];
        int c = ei[N_EDGES + e];
        int p = atomicAdd(&cur[c], 1);         // LDS atomic
        float v = di[r] * ew[e] * di[c];
        erec[p] = make_int2(r, __float_as_int(v));
    }
}

// ---------------------------------------------------------------------------
// GEMM: out[m][o] = sum_k A[m][k] * W[o][k];  A:[M][128], W:[128][128] row-major.
__global__ __launch_bounds__(256) void gemm128_kernel(const float* __restrict__ A,
                                                      const float* __restrict__ W,
                                                      float* __restrict__ out, int M) {
    __shared__ float As[32][68];
    __shared__ float Ws[32][132];
    int tid = threadIdx.x;
    int tx = tid & 31;
    int ty = tid >> 5;
    int row0 = blockIdx.x * 64;
    float acc[8][4] = {};
    for (int k0 = 0; k0 < 128; k0 += 32) {
        #pragma unroll
        for (int i = 0; i < 8; ++i) {
            int idx = tid + i * 256;
            int r = idx >> 5, k = idx & 31;
            int gr = row0 + r;
            As[k][r] = (gr < M) ? A[gr * CH + k0 + k] : 0.0f;
        }
        #pragma unroll
        for (int i = 0; i < 16; ++i) {
            int idx = tid + i * 256;
            int o = idx >> 5, k = idx & 31;
            Ws[k][o] = W[o * CH + k0 + k];
        }
        __syncthreads();
        #pragma unroll
        for (int kk = 0; kk < 32; ++kk) {
            float a[8], w[4];
            #pragma unroll
            for (int j = 0; j < 8; ++j) a[j] = As[kk][ty * 8 + j];
            #pragma unroll
            for (int c = 0; c < 4; ++c) w[c] = Ws[kk][tx * 4 + c];
            #pragma unroll
            for (int j = 0; j < 8; ++j)
                #pragma unroll
                for (int c = 0; c < 4; ++c)
                    acc[j][c] += a[j] * w[c];
        }
        __syncthreads();
    }
    #pragma unroll
    for (int j = 0; j < 8; ++j) {
        int gr = row0 + ty * 8 + j;
        if (gr < M) {
            float4 v = make_float4(acc[j][0], acc[j][1], acc[j][2], acc[j][3]);
            *reinterpret_cast<float4*>(&out[gr * CH + tx * 4]) = v;
        }
    }
}

// ---------------------------------------------------------------------------
// Aggregation: 32 lanes per node (float4/lane), 8 nodes/block, unroll x8.
__global__ __launch_bounds__(256) void agg_kernel(const float4* __restrict__ xw4,
        const int2* __restrict__ erec, const int* __restrict__ offs,
        const int* __restrict__ cnt, const float* __restrict__ dinv,
        const float4* __restrict__ bias4, float4* __restrict__ out4) {
    int l = threadIdx.x & 31;                  // channel quad
    int g = threadIdx.x >> 5;                  // node group 0..7
    int n = blockIdx.x * 8 + g;                // grid = 1250 -> n < 10000 always
    float d = dinv[n];
    float dd = d * d;
    float4 self = xw4[n * 32 + l];
    float4 acc = make_float4(dd * self.x, dd * self.y, dd * self.z, dd * self.w);
    int start = offs[n];
    int num = cnt[n];
    int i = 0;
    for (; i + 8 <= num; i += 8) {
        int2 r[8];
        #pragma unroll
        for (int j = 0; j < 8; ++j) r[j] = erec[start + i + j];
        float4 f[8];
        #pragma unroll
        for (int j = 0; j < 8; ++j) f[j] = xw4[r[j].x * 32 + l];
        #pragma unroll
        for (int j = 0; j < 8; ++j) {
            float v = __int_as_float(r[j].y);
            acc.x += v * f[j].x; acc.y += v * f[j].y;
            acc.z += v * f[j].z; acc.w += v * f[j].w;
        }
    }
    for (; i < num; ++i) {
        int2 r = erec[start + i];
        float4 f = xw4[r.x * 32 + l];
        float v = __int_as_float(r.y);
        acc.x += v * f.x; acc.y += v * f.y; acc.z += v * f.z; acc.w += v * f.w;
    }
    float4 bb = bias4[l];
    acc.x = fmaxf(acc.x + bb.x, 0.0f);
    acc.y = fmaxf(acc.y + bb.y, 0.0f);
    acc.z = fmaxf(acc.z + bb.z, 0.0f);
    acc.w = fmaxf(acc.w + bb.w, 0.0f);
    out4[n * 32 + l] = acc;
}

// ---------------------------------------------------------------------------
// Fused temporal conv(k=3) + FC: 32 lanes/node, float4 loads, 8 nodes/block.
__global__ __launch_bounds__(256) void convfc_kernel(const float4* __restrict__ h4,
        const float* __restrict__ vbuf, const float* __restrict__ c0,
        float* __restrict__ out) {
    int l = threadIdx.x & 31;
    int g = threadIdx.x >> 5;
    int n = blockIdx.x * 8 + g;                // grid = 1250
    float v00 = vbuf[(4 * l + 0) * 3 + 0], v01 = vbuf[(4 * l + 0) * 3 + 1], v02 = vbuf[(4 * l + 0) * 3 + 2];
    float v10 = vbuf[(4 * l + 1) * 3 + 0], v11 = vbuf[(4 * l + 1) * 3 + 1], v12 = vbuf[(4 * l + 1) * 3 + 2];
    float v20 = vbuf[(4 * l + 2) * 3 + 0], v21 = vbuf[(4 * l + 2) * 3 + 1], v22 = vbuf[(4 * l + 2) * 3 + 2];
    float v30 = vbuf[(4 * l + 3) * 3 + 0], v31 = vbuf[(4 * l + 3) * 3 + 1], v32 = vbuf[(4 * l + 3) * 3 + 2];
    float4 hm = h4[n * 32 + l];
    float p = hm.x * v01 + hm.y * v11 + hm.z * v21 + hm.w * v31;
    if (n > 0) {
        float4 ha = h4[(n - 1) * 32 + l];
        p += ha.x * v00 + ha.y * v10 + ha.z * v20 + ha.w * v30;
    }
    if (n < N_NODES - 1) {
        float4 hb = h4[(n + 1) * 32 + l];
        p += hb.x * v02 + hb.y * v12 + hb.z * v22 + hb.w * v32;
    }
    #pragma unroll
    for (int off = 16; off > 0; off >>= 1) p += __shfl_down(p, off, 32);
    if (l == 0) out[n] = p + *c0;
}

// ---------------------------------------------------------------------------
extern "C" void kernel_launch(void* const* d_in, const int* in_sizes, int n_in,
                              void* d_out, int out_size, void* d_ws, size_t ws_size,
                              hipStream_t stream) {
    const float* x       = (const float*)d_in[0];
    const int*   ei      = (const int*)d_in[1];
    const float* ew      = (const float*)d_in[2];
    const float* W1      = (const float*)d_in[3];
    const float* b1      = (const float*)d_in[4];
    const float* W2      = (const float*)d_in[5];
    const float* b2      = (const float*)d_in[6];
    const float* conv_w  = (const float*)d_in[7];
    const float* conv_b  = (const float*)d_in[8];
    const float* fc_w    = (const float*)d_in[9];
    const float* fc_b    = (const float*)d_in[10];
    float* out = (float*)d_out;

    // Workspace layout with stream-ordered aliasing:
    //   hist  (NHB*10000 i) aliases bufA (hist dead after scatter; bufA first
    //                                     written by gemm1, later in stream)
    //   dhist (NHB*10000 f) aliases erec (dhist dead after reduce; erec first
    //                                     written by scatter, later in stream)
    float* bufA   = (float*)d_ws;                   // 1,280,000 f
    float* bufB   = bufA + N_NODES * CH;            // 1,280,000 f
    int2*  erec   = (int2*)(bufB + N_NODES * CH);   // 640,000 x 8B
    int*   hist   = (int*)bufA;                     // alias
    float* dhist  = (float*)erec;                   // alias
    int*   tot    = (int*)(erec + N_EDGES);         // 10,000 i
    int*   offs   = tot + N_NODES;                  // 10,000 i
    float* dinv   = (float*)(offs + N_NODES);       // 10,000 f
    float* vbuf   = dinv + N_NODES;                 // 384 f
    float* c0     = vbuf + 384;                     // 1 f

    // --- CSR build, atomic-free at global scope ---
    hist_kernel<<<NHB, 256, 0, stream>>>(ei, ew, hist, dhist);
    reduce_kernel<<<NCHUNK + 1, 256, 0, stream>>>(hist, dhist, tot, dinv,
                                                  conv_w, conv_b, fc_w, fc_b, vbuf, c0);
    bofs_kernel<<<NCHUNK, 256, 0, stream>>>(hist, tot, offs);
    scatter_kernel<<<NHB, 256, 0, stream>>>(ei, ew, dinv, hist, erec);

    const int gemm_grid = (N_NODES + 63) / 64;
    // --- layer 1 ---
    gemm128_kernel<<<gemm_grid, 256, 0, stream>>>(x, W1, bufA, N_NODES);
    agg_kernel<<<N_NODES / 8, 256, 0, stream>>>((const float4*)bufA, erec, offs, tot,
                                                dinv, (const float4*)b1, (float4*)bufB);
    // --- layer 2 ---
    gemm128_kernel<<<gemm_grid, 256, 0, stream>>>(bufB, W2, bufA, N_NODES);
    agg_kernel<<<N_NODES / 8, 256, 0, stream>>>((const float4*)bufA, erec, offs, tot,
                                                dinv, (const float4*)b2, (float4*)bufB);
    // --- fused temporal conv + fc ---
    convfc_kernel<<<N_NODES / 8, 256, 0, stream>>>((const float4*)bufB, vbuf, c0, out);
}